// Round 3
// baseline (322.077 us; speedup 1.0000x reference)
//
#include <hip/hip_runtime.h>

constexpr int B = 16, N = 128, D = 128, DN0 = 64, DE0 = 16;

typedef _Float16 half8 __attribute__((ext_vector_type(8)));
typedef _Float16 half4 __attribute__((ext_vector_type(4)));
typedef float floatx4 __attribute__((ext_vector_type(4)));

// ---------------------------------------------------------------------------
// K0: WeT prep. WeT_l[c][k] = (fp16) w_msg_l[2D+k][c], layers 1 and 2.
// ---------------------------------------------------------------------------
__global__ __launch_bounds__(128) void k_wprep(
    const float* __restrict__ wm1, const float* __restrict__ wm2,
    _Float16* __restrict__ weT1, _Float16* __restrict__ weT2) {
  const int bid = blockIdx.x;            // 256 blocks
  const int layer = bid >> 7, c = bid & 127;
  const int k = threadIdx.x;
  const float* src = layer ? wm2 : wm1;
  _Float16* dst = layer ? weT2 : weT1;
  dst[c * D + k] = (_Float16)src[(2 * D + k) * D + c];
}

// ---------------------------------------------------------------------------
// K1: xi0 = x @ Wi0 + b_msg0 ; xj0 = x @ Wj0      (2048 blocks)
// ---------------------------------------------------------------------------
__global__ __launch_bounds__(128) void k_pre0(
    const float* __restrict__ x, const float* __restrict__ wm0,
    const float* __restrict__ bm0,
    float* __restrict__ xi0, float* __restrict__ xj0) {
  const int row = blockIdx.x;
  const int c = threadIdx.x;
  __shared__ float xr[DN0];
  if (c < DN0) xr[c] = x[row * DN0 + c];
  __syncthreads();
  float ai = bm0[c], aj = 0.f;
  #pragma unroll 8
  for (int k = 0; k < DN0; ++k) {
    const float xv = xr[k];
    ai = fmaf(xv, wm0[k * D + c], ai);
    aj = fmaf(xv, wm0[(DN0 + k) * D + c], aj);
  }
  xi0[row * D + c] = ai;
  xj0[row * D + c] = aj;
}

// ---------------------------------------------------------------------------
// K2: layer-0 edge kernel (K=16, VALU fp32). Thread t: c4=(t&31)*4, jb=t>>5,
// j = jb+8p. half4 stores -> 256 B contiguous per 32-lane group.
// ---------------------------------------------------------------------------
__global__ __launch_bounds__(256) void k_edge0(
    const int* __restrict__ ei, const float* __restrict__ eattr,
    const float* __restrict__ wm0,
    const float* __restrict__ xi0, const float* __restrict__ xj0,
    _Float16* __restrict__ msg0, float* __restrict__ agg0) {
  const int row = blockIdx.x;
  const int b = row >> 7;
  const int t = threadIdx.x;
  const int c4 = (t & 31) * 4, jb = t >> 5;

  __shared__ float e_row[N][20];
  __shared__ float w_t[DE0][D];
  __shared__ float amask[N];
  __shared__ float xi_r[D];
  __shared__ float hp2[8][32][4];

  const float4* esrc = (const float4*)(eattr + (size_t)row * N * DE0);
  const float4* wsrc = (const float4*)(wm0 + 2 * DN0 * D);
  #pragma unroll
  for (int u = 0; u < 2; ++u) {
    const int idx4 = u * 256 + t;
    const int j = idx4 >> 2;
    const int k4 = (idx4 & 3) * 4;
    *(float4*)&e_row[j][k4] = esrc[idx4];
    ((float4*)&w_t[0][0])[idx4] = wsrc[idx4];
  }
  if (t < N) {
    amask[t] = (float)ei[(size_t)row * N + t];
    xi_r[t] = xi0[row * D + t];
  }
  __syncthreads();

  float acc[16][4] = {};
  #pragma unroll 4
  for (int k = 0; k < DE0; ++k) {
    float av[16];
    #pragma unroll
    for (int p = 0; p < 16; ++p) av[p] = e_row[jb + 8 * p][k];
    const floatx4 wv = *(const floatx4*)&w_t[k][c4];
    #pragma unroll
    for (int p = 0; p < 16; ++p)
      #pragma unroll
      for (int q = 0; q < 4; ++q)
        acc[p][q] = fmaf(av[p], wv[q], acc[p][q]);
  }

  float hq[4] = {};
  const float* xjb = xj0 + (size_t)b * N * D;
  _Float16* mrow = msg0 + (size_t)row * N * D;
  const floatx4 xiv = *(const floatx4*)&xi_r[c4];
  #pragma unroll
  for (int p = 0; p < 16; ++p) {
    const int j = jb + 8 * p;
    const float am = amask[j];
    const floatx4 xjv = *(const floatx4*)&xjb[j * D + c4];
    half4 hv;
    #pragma unroll
    for (int q = 0; q < 4; ++q) {
      float v = xiv[q] + xjv[q] + acc[p][q];
      v = fmaxf(v, 0.f) * am;
      hv[q] = (_Float16)v;
      hq[q] += v;
    }
    *(half4*)&mrow[j * D + c4] = hv;
  }
  #pragma unroll
  for (int q = 0; q < 4; ++q) hp2[jb][t & 31][q] = hq[q];
  __syncthreads();
  if (t < D) {
    float s = 0.f;
    #pragma unroll
    for (int g = 0; g < 8; ++g) s += hp2[g][t >> 2][t & 3];
    agg0[row * D + t] = s;
  }
}

// ---------------------------------------------------------------------------
// K3 / K5: node update + next layer's xi/xj precompute.
// ---------------------------------------------------------------------------
__global__ __launch_bounds__(128) void k_node0(
    const float* __restrict__ x0, const float* __restrict__ agg0,
    const float* __restrict__ wn0, const float* __restrict__ bn0,
    const float* __restrict__ wm1, const float* __restrict__ bm1,
    float* __restrict__ x1, float* __restrict__ xi1, float* __restrict__ xj1) {
  const int row = blockIdx.x;
  const int c = threadIdx.x;
  __shared__ float xr[DN0], ar[D], x1r[D];
  if (c < DN0) xr[c] = x0[row * DN0 + c];
  ar[c] = agg0[row * D + c];
  __syncthreads();
  float a = bn0[c];
  #pragma unroll 8
  for (int k = 0; k < DN0; ++k) a = fmaf(xr[k], wn0[k * D + c], a);
  #pragma unroll 8
  for (int k = 0; k < D; ++k) a = fmaf(ar[k], wn0[(DN0 + k) * D + c], a);
  a = fmaxf(a, 0.f);
  x1[row * D + c] = a;
  x1r[c] = a;
  __syncthreads();
  float ai = bm1[c], aj = 0.f;
  #pragma unroll 8
  for (int k = 0; k < D; ++k) {
    const float xv = x1r[k];
    ai = fmaf(xv, wm1[k * D + c], ai);
    aj = fmaf(xv, wm1[(D + k) * D + c], aj);
  }
  xi1[row * D + c] = ai;
  xj1[row * D + c] = aj;
}

__global__ __launch_bounds__(128) void k_node1(
    const float* __restrict__ x1, const float* __restrict__ agg1,
    const float* __restrict__ wn1, const float* __restrict__ bn1,
    const float* __restrict__ wm2, const float* __restrict__ bm2,
    float* __restrict__ xi2, float* __restrict__ xj2) {
  const int row = blockIdx.x;
  const int c = threadIdx.x;
  __shared__ float x1r[D], ar[D], x2r[D];
  x1r[c] = x1[row * D + c];
  ar[c] = agg1[row * D + c];
  __syncthreads();
  float a = bn1[c];
  #pragma unroll 8
  for (int k = 0; k < D; ++k) a = fmaf(x1r[k], wn1[k * D + c], a);
  #pragma unroll 8
  for (int k = 0; k < D; ++k) a = fmaf(ar[k], wn1[(D + k) * D + c], a);
  x2r[c] = 0.5f * (x1r[c] + fmaxf(a, 0.f));
  __syncthreads();
  float ai = bm2[c], aj = 0.f;
  #pragma unroll 8
  for (int k = 0; k < D; ++k) {
    const float xv = x2r[k];
    ai = fmaf(xv, wm2[k * D + c], ai);
    aj = fmaf(xv, wm2[(D + k) * D + c], aj);
  }
  xi2[row * D + c] = ai;
  xj2[row * D + c] = aj;
}

// ---------------------------------------------------------------------------
// K4: fused layer-1 edge + layer-2 matmul. One block per (b,i) row.
// Pass 1: T1 = We1T x msg0 -> msg1 -> agg1; e_mid = 0.5(msg0+msg1) RMW in LDS.
// Pass 2: T2 = We2T x e_mid -> deposited in LDS -> coalesced copy-out over em.
// LDS is XOR-swizzled in 16B cells (cell ^ (j&15)): conflict-free everywhere.
// Waves own j-rows [32w,32w+32) exclusively: no barrier between passes.
// ---------------------------------------------------------------------------
__global__ __launch_bounds__(256, 4) void k_mid(
    const int* __restrict__ ei, const _Float16* __restrict__ weT1,
    const _Float16* __restrict__ weT2,
    const float* __restrict__ xi, const float* __restrict__ xj,
    _Float16* __restrict__ em,          // in: msg0, out: T2
    float* __restrict__ aggout) {
  const int row = blockIdx.x;
  const int b = row >> 7;
  const int t = threadIdx.x;
  const int w = t >> 6;
  const int lane = t & 63;
  const int lm = lane & 15;
  const int lq = lane >> 4;

  __shared__ uint4 sE4[N * 16];        // 32 KB, swizzled cells
  __shared__ float sXi[D];
  __shared__ float sMask[N];
  __shared__ float sHp[4][D];
  _Float16* sEh = (_Float16*)sE4;

  // --- stage msg0 row into swizzled LDS ---
  const uint4* esrc = (const uint4*)(em + (size_t)row * N * D);
  #pragma unroll
  for (int u = 0; u < 8; ++u) {
    const int idx4 = u * 256 + t;
    const int j = idx4 >> 4, g = idx4 & 15;
    sE4[j * 16 + (g ^ (j & 15))] = esrc[idx4];
  }
  if (t < N) {
    sMask[t] = (float)ei[(size_t)row * N + t];
    sXi[t] = xi[row * D + t];
  }
  __syncthreads();

  // --- pass 1: T1 = We1T (A) x msg0 (B) ---
  floatx4 acc[8][2];
  #pragma unroll
  for (int ct = 0; ct < 8; ++ct)
    #pragma unroll
    for (int jt = 0; jt < 2; ++jt)
      acc[ct][jt] = (floatx4){0.f, 0.f, 0.f, 0.f};

  #pragma unroll
  for (int ks = 0; ks < 4; ++ks) {
    const int sw = (lq + 4 * ks) ^ lm;
    const half8 bv0 = *(const half8*)&sEh[((32 * w + lm) * 16 + sw) * 8];
    const half8 bv1 = *(const half8*)&sEh[((32 * w + 16 + lm) * 16 + sw) * 8];
    #pragma unroll
    for (int ct = 0; ct < 8; ++ct) {
      const half8 av = *(const half8*)(weT1 + (16 * ct + lm) * D + 8 * lq + 32 * ks);
      acc[ct][0] = __builtin_amdgcn_mfma_f32_16x16x32_f16(av, bv0, acc[ct][0], 0, 0, 0);
      acc[ct][1] = __builtin_amdgcn_mfma_f32_16x16x32_f16(av, bv1, acc[ct][1], 0, 0, 0);
    }
  }

  // --- epilogue 1: msg1, agg partial, e_mid RMW into sE ---
  floatx4 xiv[8];
  #pragma unroll
  for (int ct = 0; ct < 8; ++ct) xiv[ct] = *(const floatx4*)&sXi[16 * ct + 4 * lq];

  const float* xjb = xj + (size_t)b * N * D;
  floatx4 hacc[8];
  #pragma unroll
  for (int ct = 0; ct < 8; ++ct) hacc[ct] = (floatx4){0.f, 0.f, 0.f, 0.f};

  #pragma unroll
  for (int jt = 0; jt < 2; ++jt) {
    const int j = 32 * w + 16 * jt + lm;
    const float am = sMask[j];
    #pragma unroll
    for (int ct = 0; ct < 8; ++ct) {
      const floatx4 xjv = *(const floatx4*)&xjb[j * D + 16 * ct + 4 * lq];
      const int cell = (2 * ct + (lq >> 1)) ^ lm;
      const int hidx = (j * 16 + cell) * 8 + (lq & 1) * 4;
      const half4 m0 = *(const half4*)&sEh[hidx];
      half4 mid;
      floatx4 m1;
      #pragma unroll
      for (int r = 0; r < 4; ++r) {
        float v = xiv[ct][r] + xjv[r] + acc[ct][jt][r];
        m1[r] = fmaxf(v, 0.f) * am;
        mid[r] = (_Float16)(0.5f * ((float)m0[r] + m1[r]));
      }
      *(half4*)&sEh[hidx] = mid;      // own rows: same-wave DS order is safe
      hacc[ct] += m1;
    }
  }

  // --- pass 2: T2 = We2T (A) x e_mid (B), reuse acc ---
  #pragma unroll
  for (int ct = 0; ct < 8; ++ct)
    #pragma unroll
    for (int jt = 0; jt < 2; ++jt)
      acc[ct][jt] = (floatx4){0.f, 0.f, 0.f, 0.f};

  #pragma unroll
  for (int ks = 0; ks < 4; ++ks) {
    const int sw = (lq + 4 * ks) ^ lm;
    const half8 bv0 = *(const half8*)&sEh[((32 * w + lm) * 16 + sw) * 8];
    const half8 bv1 = *(const half8*)&sEh[((32 * w + 16 + lm) * 16 + sw) * 8];
    #pragma unroll
    for (int ct = 0; ct < 8; ++ct) {
      const half8 av = *(const half8*)(weT2 + (16 * ct + lm) * D + 8 * lq + 32 * ks);
      acc[ct][0] = __builtin_amdgcn_mfma_f32_16x16x32_f16(av, bv0, acc[ct][0], 0, 0, 0);
      acc[ct][1] = __builtin_amdgcn_mfma_f32_16x16x32_f16(av, bv1, acc[ct][1], 0, 0, 0);
    }
  }

  // --- deposit T2 (fp16) into sE, C-layout cells ---
  #pragma unroll
  for (int jt = 0; jt < 2; ++jt) {
    const int j = 32 * w + 16 * jt + lm;
    #pragma unroll
    for (int ct = 0; ct < 8; ++ct) {
      const int cell = (2 * ct + (lq >> 1)) ^ lm;
      const int hidx = (j * 16 + cell) * 8 + (lq & 1) * 4;
      half4 tv;
      #pragma unroll
      for (int r = 0; r < 4; ++r) tv[r] = (_Float16)acc[ct][jt][r];
      *(half4*)&sEh[hidx] = tv;
    }
  }

  // --- agg1: shuffle reduce over lm, cross-wave via sHp ---
  #pragma unroll
  for (int m = 1; m < 16; m <<= 1)
    #pragma unroll
    for (int ct = 0; ct < 8; ++ct)
      #pragma unroll
      for (int r = 0; r < 4; ++r)
        hacc[ct][r] += __shfl_xor(hacc[ct][r], m, 64);
  if (lm == 0) {
    #pragma unroll
    for (int ct = 0; ct < 8; ++ct)
      *(floatx4*)&sHp[w][16 * ct + 4 * lq] = hacc[ct];
  }
  __syncthreads();
  if (t < D)
    aggout[row * D + t] = sHp[0][t] + sHp[1][t] + sHp[2][t] + sHp[3][t];

  // --- coalesced T2 copy-out (overwrites msg0/em) ---
  uint4* dst = (uint4*)(em + (size_t)row * N * D);
  #pragma unroll
  for (int u = 0; u < 8; ++u) {
    const int idx4 = u * 256 + t;
    const int j = idx4 >> 4, g = idx4 & 15;
    dst[idx4] = sE4[j * 16 + (g ^ (j & 15))];
  }
}

// ---------------------------------------------------------------------------
// K6: final layer streaming: msg2 = relu(xi2 + xj2 + T2)*A; rowsum over j.
// Thread t: channels c8=(t&15)*8, j residue jr=t>>4 (8 j's per thread).
// ---------------------------------------------------------------------------
__global__ __launch_bounds__(256) void k_fin(
    const int* __restrict__ ei, const _Float16* __restrict__ t2,
    const float* __restrict__ xi, const float* __restrict__ xj,
    float* __restrict__ rowsum) {
  const int row = blockIdx.x;
  const int b = row >> 7;
  const int t = threadIdx.x;
  const int c8 = (t & 15) * 8, jr = t >> 4;

  __shared__ float sMask[N];
  __shared__ float hp[16][16][8];
  if (t < N) sMask[t] = (float)ei[(size_t)row * N + t];
  float xiv[8];
  *(floatx4*)&xiv[0] = *(const floatx4*)&xi[row * D + c8];
  *(floatx4*)&xiv[4] = *(const floatx4*)&xi[row * D + c8 + 4];
  __syncthreads();

  const uint4* src = (const uint4*)(t2 + (size_t)row * N * D);
  const float* xjb = xj + (size_t)b * N * D;
  float acc8[8] = {};
  #pragma unroll
  for (int u = 0; u < 8; ++u) {
    const int j = u * 16 + jr;
    const uint4 raw = src[u * 256 + t];
    const half8 tv = *(const half8*)&raw;
    const float am = sMask[j];
    const floatx4 xj0 = *(const floatx4*)&xjb[j * D + c8];
    const floatx4 xj1 = *(const floatx4*)&xjb[j * D + c8 + 4];
    #pragma unroll
    for (int r = 0; r < 4; ++r) {
      acc8[r]     += fmaxf(xiv[r] + xj0[r] + (float)tv[r], 0.f) * am;
      acc8[4 + r] += fmaxf(xiv[4 + r] + xj1[r] + (float)tv[4 + r], 0.f) * am;
    }
  }
  #pragma unroll
  for (int k = 0; k < 8; ++k) hp[jr][t & 15][k] = acc8[k];
  __syncthreads();
  if (t < D) {
    float s = 0.f;
    #pragma unroll
    for (int g = 0; g < 16; ++g) s += hp[g][t >> 3][t & 7];
    rowsum[row * D + t] = s;
  }
}

// ---------------------------------------------------------------------------
// K7: head MLP. 16 blocks.
// ---------------------------------------------------------------------------
__global__ __launch_bounds__(128) void k_head(
    const float* __restrict__ rowsum,
    const float* __restrict__ w1, const float* __restrict__ b1,
    const float* __restrict__ w2, const float* __restrict__ b2,
    const float* __restrict__ w3, const float* __restrict__ b3,
    float* __restrict__ out) {
  const int b = blockIdx.x;
  const int c = threadIdx.x;
  __shared__ float hr[D], h1r[D], h2r[D];
  const float* rs = rowsum + (size_t)b * N * D;
  float s = 0.f;
  for (int i = 0; i < N; ++i) s += rs[i * D + c];
  hr[c] = s * (1.f / (N * N));
  __syncthreads();
  float a = b1[c];
  #pragma unroll 8
  for (int k = 0; k < D; ++k) a = fmaf(hr[k], w1[k * D + c], a);
  h1r[c] = fmaxf(a, 0.f);
  __syncthreads();
  a = b2[c];
  #pragma unroll 8
  for (int k = 0; k < D; ++k) a = fmaf(h1r[k], w2[k * D + c], a);
  h2r[c] = fmaxf(a, 0.f);
  __syncthreads();
  hr[c] = h2r[c] * w3[c];
  __syncthreads();
  if (c == 0) {
    float s2 = b3[0];
    for (int k = 0; k < D; ++k) s2 += hr[k];
    out[b] = s2;
  }
}

// ---------------------------------------------------------------------------
extern "C" void kernel_launch(void* const* d_in, const int* in_sizes, int n_in,
                              void* d_out, int out_size, void* d_ws, size_t ws_size,
                              hipStream_t stream) {
  const int*   ei  = (const int*)d_in[0];
  const float* x0  = (const float*)d_in[1];
  const float* ea  = (const float*)d_in[2];
  const float* wm0 = (const float*)d_in[3];
  const float* bm0 = (const float*)d_in[4];
  const float* wn0 = (const float*)d_in[5];
  const float* bn0 = (const float*)d_in[6];
  const float* wm1 = (const float*)d_in[7];
  const float* bm1 = (const float*)d_in[8];
  const float* wn1 = (const float*)d_in[9];
  const float* bn1 = (const float*)d_in[10];
  const float* wm2 = (const float*)d_in[11];
  const float* bm2 = (const float*)d_in[12];
  const float* wh1 = (const float*)d_in[15];
  const float* bh1 = (const float*)d_in[16];
  const float* wh2 = (const float*)d_in[17];
  const float* bh2 = (const float*)d_in[18];
  const float* wh3 = (const float*)d_in[19];
  const float* bh3 = (const float*)d_in[20];
  float* out = (float*)d_out;

  _Float16* msg0h = (_Float16*)d_ws;                 // [B,N,N,D] fp16: msg0 -> T2
  _Float16* weT1  = msg0h + (size_t)B * N * N * D;
  _Float16* weT2  = weT1 + D * D;
  float* f = (float*)(weT2 + D * D);
  size_t off = 0;
  const size_t R = (size_t)B * N * D;
  float* xi0  = f + off; off += R;
  float* xj0  = f + off; off += R;
  float* agg0 = f + off; off += R;
  float* x1   = f + off; off += R;
  float* xi1  = f + off; off += R;
  float* xj1  = f + off; off += R;
  float* agg1 = f + off; off += R;
  float* xi2  = f + off; off += R;
  float* xj2  = f + off; off += R;
  float* rsum = f + off; off += R;

  const int rows = B * N;   // 2048
  k_wprep<<<256, 128, 0, stream>>>(wm1, wm2, weT1, weT2);
  k_pre0 <<<rows, 128, 0, stream>>>(x0, wm0, bm0, xi0, xj0);
  k_edge0<<<rows, 256, 0, stream>>>(ei, ea, wm0, xi0, xj0, msg0h, agg0);
  k_node0<<<rows, 128, 0, stream>>>(x0, agg0, wn0, bn0, wm1, bm1, x1, xi1, xj1);
  k_mid  <<<rows, 256, 0, stream>>>(ei, weT1, weT2, xi1, xj1, msg0h, agg1);
  k_node1<<<rows, 128, 0, stream>>>(x1, agg1, wn1, bn1, wm2, bm2, xi2, xj2);
  k_fin  <<<rows, 256, 0, stream>>>(ei, msg0h, xi2, xj2, rsum);
  k_head <<<B,    128, 0, stream>>>(rsum, wh1, bh1, wh2, bh2, wh3, bh3, out);
}

// Round 4
// 298.151 us; speedup vs baseline: 1.0802x; 1.0802x over previous
//
#include <hip/hip_runtime.h>

constexpr int B = 16, N = 128, D = 128, DN0 = 64, DE0 = 16;

typedef _Float16 half8 __attribute__((ext_vector_type(8)));
typedef _Float16 half4 __attribute__((ext_vector_type(4)));
typedef float floatx4 __attribute__((ext_vector_type(4)));

// ---------------------------------------------------------------------------
// K0: WeT prep. WeT_l[c][k] = (fp16) w_msg_l[2D+k][c], layers 1 and 2.
// ---------------------------------------------------------------------------
__global__ __launch_bounds__(128) void k_wprep(
    const float* __restrict__ wm1, const float* __restrict__ wm2,
    _Float16* __restrict__ weT1, _Float16* __restrict__ weT2) {
  const int bid = blockIdx.x;            // 256 blocks
  const int layer = bid >> 7, c = bid & 127;
  const int k = threadIdx.x;
  const float* src = layer ? wm2 : wm1;
  _Float16* dst = layer ? weT2 : weT1;
  dst[c * D + k] = (_Float16)src[(2 * D + k) * D + c];
}

// ---------------------------------------------------------------------------
// K1: xi0 = x @ Wi0 + b_msg0 ; xj0 = x @ Wj0      (2048 blocks)
// ---------------------------------------------------------------------------
__global__ __launch_bounds__(128) void k_pre0(
    const float* __restrict__ x, const float* __restrict__ wm0,
    const float* __restrict__ bm0,
    float* __restrict__ xi0, float* __restrict__ xj0) {
  const int row = blockIdx.x;
  const int c = threadIdx.x;
  __shared__ float xr[DN0];
  if (c < DN0) xr[c] = x[row * DN0 + c];
  __syncthreads();
  float ai = bm0[c], aj = 0.f;
  #pragma unroll 8
  for (int k = 0; k < DN0; ++k) {
    const float xv = xr[k];
    ai = fmaf(xv, wm0[k * D + c], ai);
    aj = fmaf(xv, wm0[(DN0 + k) * D + c], aj);
  }
  xi0[row * D + c] = ai;
  xj0[row * D + c] = aj;
}

// ---------------------------------------------------------------------------
// K2: layer-0 edge kernel (K=16, VALU fp32). Thread t: c4=(t&31)*4, jb=t>>5,
// j = jb+8p. half4 stores -> 256 B contiguous per 32-lane group.
// ---------------------------------------------------------------------------
__global__ __launch_bounds__(256) void k_edge0(
    const int* __restrict__ ei, const float* __restrict__ eattr,
    const float* __restrict__ wm0,
    const float* __restrict__ xi0, const float* __restrict__ xj0,
    _Float16* __restrict__ msg0, float* __restrict__ agg0) {
  const int row = blockIdx.x;
  const int b = row >> 7;
  const int t = threadIdx.x;
  const int c4 = (t & 31) * 4, jb = t >> 5;

  __shared__ float e_row[N][20];
  __shared__ float w_t[DE0][D];
  __shared__ float amask[N];
  __shared__ float xi_r[D];
  __shared__ float hp2[8][32][4];

  const float4* esrc = (const float4*)(eattr + (size_t)row * N * DE0);
  const float4* wsrc = (const float4*)(wm0 + 2 * DN0 * D);
  #pragma unroll
  for (int u = 0; u < 2; ++u) {
    const int idx4 = u * 256 + t;
    const int j = idx4 >> 2;
    const int k4 = (idx4 & 3) * 4;
    *(float4*)&e_row[j][k4] = esrc[idx4];
    ((float4*)&w_t[0][0])[idx4] = wsrc[idx4];
  }
  if (t < N) {
    amask[t] = (float)ei[(size_t)row * N + t];
    xi_r[t] = xi0[row * D + t];
  }
  __syncthreads();

  float acc[16][4] = {};
  #pragma unroll 4
  for (int k = 0; k < DE0; ++k) {
    float av[16];
    #pragma unroll
    for (int p = 0; p < 16; ++p) av[p] = e_row[jb + 8 * p][k];
    const floatx4 wv = *(const floatx4*)&w_t[k][c4];
    #pragma unroll
    for (int p = 0; p < 16; ++p)
      #pragma unroll
      for (int q = 0; q < 4; ++q)
        acc[p][q] = fmaf(av[p], wv[q], acc[p][q]);
  }

  float hq[4] = {};
  const float* xjb = xj0 + (size_t)b * N * D;
  _Float16* mrow = msg0 + (size_t)row * N * D;
  const floatx4 xiv = *(const floatx4*)&xi_r[c4];
  #pragma unroll
  for (int p = 0; p < 16; ++p) {
    const int j = jb + 8 * p;
    const float am = amask[j];
    const floatx4 xjv = *(const floatx4*)&xjb[j * D + c4];
    half4 hv;
    #pragma unroll
    for (int q = 0; q < 4; ++q) {
      float v = xiv[q] + xjv[q] + acc[p][q];
      v = fmaxf(v, 0.f) * am;
      hv[q] = (_Float16)v;
      hq[q] += v;
    }
    *(half4*)&mrow[j * D + c4] = hv;
  }
  #pragma unroll
  for (int q = 0; q < 4; ++q) hp2[jb][t & 31][q] = hq[q];
  __syncthreads();
  if (t < D) {
    float s = 0.f;
    #pragma unroll
    for (int g = 0; g < 8; ++g) s += hp2[g][t >> 2][t & 3];
    agg0[row * D + t] = s;
  }
}

// ---------------------------------------------------------------------------
// K3 / K5: node update + next layer's xi/xj precompute.
// ---------------------------------------------------------------------------
__global__ __launch_bounds__(128) void k_node0(
    const float* __restrict__ x0, const float* __restrict__ agg0,
    const float* __restrict__ wn0, const float* __restrict__ bn0,
    const float* __restrict__ wm1, const float* __restrict__ bm1,
    float* __restrict__ x1, float* __restrict__ xi1, float* __restrict__ xj1) {
  const int row = blockIdx.x;
  const int c = threadIdx.x;
  __shared__ float xr[DN0], ar[D], x1r[D];
  if (c < DN0) xr[c] = x0[row * DN0 + c];
  ar[c] = agg0[row * D + c];
  __syncthreads();
  float a = bn0[c];
  #pragma unroll 8
  for (int k = 0; k < DN0; ++k) a = fmaf(xr[k], wn0[k * D + c], a);
  #pragma unroll 8
  for (int k = 0; k < D; ++k) a = fmaf(ar[k], wn0[(DN0 + k) * D + c], a);
  a = fmaxf(a, 0.f);
  x1[row * D + c] = a;
  x1r[c] = a;
  __syncthreads();
  float ai = bm1[c], aj = 0.f;
  #pragma unroll 8
  for (int k = 0; k < D; ++k) {
    const float xv = x1r[k];
    ai = fmaf(xv, wm1[k * D + c], ai);
    aj = fmaf(xv, wm1[(D + k) * D + c], aj);
  }
  xi1[row * D + c] = ai;
  xj1[row * D + c] = aj;
}

__global__ __launch_bounds__(128) void k_node1(
    const float* __restrict__ x1, const float* __restrict__ agg1,
    const float* __restrict__ wn1, const float* __restrict__ bn1,
    const float* __restrict__ wm2, const float* __restrict__ bm2,
    float* __restrict__ xi2, float* __restrict__ xj2) {
  const int row = blockIdx.x;
  const int c = threadIdx.x;
  __shared__ float x1r[D], ar[D], x2r[D];
  x1r[c] = x1[row * D + c];
  ar[c] = agg1[row * D + c];
  __syncthreads();
  float a = bn1[c];
  #pragma unroll 8
  for (int k = 0; k < D; ++k) a = fmaf(x1r[k], wn1[k * D + c], a);
  #pragma unroll 8
  for (int k = 0; k < D; ++k) a = fmaf(ar[k], wn1[(D + k) * D + c], a);
  x2r[c] = 0.5f * (x1r[c] + fmaxf(a, 0.f));
  __syncthreads();
  float ai = bm2[c], aj = 0.f;
  #pragma unroll 8
  for (int k = 0; k < D; ++k) {
    const float xv = x2r[k];
    ai = fmaf(xv, wm2[k * D + c], ai);
    aj = fmaf(xv, wm2[(D + k) * D + c], aj);
  }
  xi2[row * D + c] = ai;
  xj2[row * D + c] = aj;
}

// ---------------------------------------------------------------------------
// K4: fused layer-1 edge + layer-2 matmul. One block per (b,i) row.
// Pass 1: T1 = We1T x msg0 -> msg1 -> agg1; e_mid = 0.5(msg0+msg1) RMW in LDS.
// Pass 2: T2 = We2T x e_mid -> deposited in LDS -> coalesced copy-out over em.
// LDS is XOR-swizzled in 16B cells (cell ^ (j&15)): conflict-free everywhere.
// Waves own j-rows [32w,32w+32) exclusively: no barrier between passes.
// __launch_bounds__(256, 2): 256-VGPR budget. (256,4) forced a 128-reg cap
// and the compiler spilled ~140 MB of scratch to HBM (R3: WRITE_SIZE 207 MB).
// ---------------------------------------------------------------------------
__global__ __launch_bounds__(256, 2) void k_mid(
    const int* __restrict__ ei, const _Float16* __restrict__ weT1,
    const _Float16* __restrict__ weT2,
    const float* __restrict__ xi, const float* __restrict__ xj,
    _Float16* __restrict__ em,          // in: msg0, out: T2
    float* __restrict__ aggout) {
  const int row = blockIdx.x;
  const int b = row >> 7;
  const int t = threadIdx.x;
  const int w = t >> 6;
  const int lane = t & 63;
  const int lm = lane & 15;
  const int lq = lane >> 4;

  __shared__ uint4 sE4[N * 16];        // 32 KB, swizzled cells
  __shared__ float sXi[D];
  __shared__ float sMask[N];
  __shared__ float sHp[4][D];
  _Float16* sEh = (_Float16*)sE4;

  // --- stage msg0 row into swizzled LDS ---
  const uint4* esrc = (const uint4*)(em + (size_t)row * N * D);
  #pragma unroll
  for (int u = 0; u < 8; ++u) {
    const int idx4 = u * 256 + t;
    const int j = idx4 >> 4, g = idx4 & 15;
    sE4[j * 16 + (g ^ (j & 15))] = esrc[idx4];
  }
  if (t < N) {
    sMask[t] = (float)ei[(size_t)row * N + t];
    sXi[t] = xi[row * D + t];
  }
  __syncthreads();

  // --- pass 1: T1 = We1T (A) x msg0 (B) ---
  floatx4 acc[8][2];
  #pragma unroll
  for (int ct = 0; ct < 8; ++ct)
    #pragma unroll
    for (int jt = 0; jt < 2; ++jt)
      acc[ct][jt] = (floatx4){0.f, 0.f, 0.f, 0.f};

  #pragma unroll
  for (int ks = 0; ks < 4; ++ks) {
    const int sw = (lq + 4 * ks) ^ lm;
    const half8 bv0 = *(const half8*)&sEh[((32 * w + lm) * 16 + sw) * 8];
    const half8 bv1 = *(const half8*)&sEh[((32 * w + 16 + lm) * 16 + sw) * 8];
    #pragma unroll
    for (int ct = 0; ct < 8; ++ct) {
      const half8 av = *(const half8*)(weT1 + (16 * ct + lm) * D + 8 * lq + 32 * ks);
      acc[ct][0] = __builtin_amdgcn_mfma_f32_16x16x32_f16(av, bv0, acc[ct][0], 0, 0, 0);
      acc[ct][1] = __builtin_amdgcn_mfma_f32_16x16x32_f16(av, bv1, acc[ct][1], 0, 0, 0);
    }
  }

  // --- epilogue 1: msg1, agg partial, e_mid RMW into sE ---
  floatx4 xiv[8];
  #pragma unroll
  for (int ct = 0; ct < 8; ++ct) xiv[ct] = *(const floatx4*)&sXi[16 * ct + 4 * lq];

  const float* xjb = xj + (size_t)b * N * D;
  floatx4 hacc[8];
  #pragma unroll
  for (int ct = 0; ct < 8; ++ct) hacc[ct] = (floatx4){0.f, 0.f, 0.f, 0.f};

  #pragma unroll
  for (int jt = 0; jt < 2; ++jt) {
    const int j = 32 * w + 16 * jt + lm;
    const float am = sMask[j];
    #pragma unroll
    for (int ct = 0; ct < 8; ++ct) {
      const floatx4 xjv = *(const floatx4*)&xjb[j * D + 16 * ct + 4 * lq];
      const int cell = (2 * ct + (lq >> 1)) ^ lm;
      const int hidx = (j * 16 + cell) * 8 + (lq & 1) * 4;
      const half4 m0 = *(const half4*)&sEh[hidx];
      half4 mid;
      floatx4 m1;
      #pragma unroll
      for (int r = 0; r < 4; ++r) {
        float v = xiv[ct][r] + xjv[r] + acc[ct][jt][r];
        m1[r] = fmaxf(v, 0.f) * am;
        mid[r] = (_Float16)(0.5f * ((float)m0[r] + m1[r]));
      }
      *(half4*)&sEh[hidx] = mid;      // own rows: same-wave DS order is safe
      hacc[ct] += m1;
    }
  }

  // --- pass 2: T2 = We2T (A) x e_mid (B), reuse acc ---
  #pragma unroll
  for (int ct = 0; ct < 8; ++ct)
    #pragma unroll
    for (int jt = 0; jt < 2; ++jt)
      acc[ct][jt] = (floatx4){0.f, 0.f, 0.f, 0.f};

  #pragma unroll
  for (int ks = 0; ks < 4; ++ks) {
    const int sw = (lq + 4 * ks) ^ lm;
    const half8 bv0 = *(const half8*)&sEh[((32 * w + lm) * 16 + sw) * 8];
    const half8 bv1 = *(const half8*)&sEh[((32 * w + 16 + lm) * 16 + sw) * 8];
    #pragma unroll
    for (int ct = 0; ct < 8; ++ct) {
      const half8 av = *(const half8*)(weT2 + (16 * ct + lm) * D + 8 * lq + 32 * ks);
      acc[ct][0] = __builtin_amdgcn_mfma_f32_16x16x32_f16(av, bv0, acc[ct][0], 0, 0, 0);
      acc[ct][1] = __builtin_amdgcn_mfma_f32_16x16x32_f16(av, bv1, acc[ct][1], 0, 0, 0);
    }
  }

  // --- deposit T2 (fp16) into sE, C-layout cells ---
  #pragma unroll
  for (int jt = 0; jt < 2; ++jt) {
    const int j = 32 * w + 16 * jt + lm;
    #pragma unroll
    for (int ct = 0; ct < 8; ++ct) {
      const int cell = (2 * ct + (lq >> 1)) ^ lm;
      const int hidx = (j * 16 + cell) * 8 + (lq & 1) * 4;
      half4 tv;
      #pragma unroll
      for (int r = 0; r < 4; ++r) tv[r] = (_Float16)acc[ct][jt][r];
      *(half4*)&sEh[hidx] = tv;
    }
  }

  // --- agg1: shuffle reduce over lm, cross-wave via sHp ---
  #pragma unroll
  for (int m = 1; m < 16; m <<= 1)
    #pragma unroll
    for (int ct = 0; ct < 8; ++ct)
      #pragma unroll
      for (int r = 0; r < 4; ++r)
        hacc[ct][r] += __shfl_xor(hacc[ct][r], m, 64);
  if (lm == 0) {
    #pragma unroll
    for (int ct = 0; ct < 8; ++ct)
      *(floatx4*)&sHp[w][16 * ct + 4 * lq] = hacc[ct];
  }
  __syncthreads();
  if (t < D)
    aggout[row * D + t] = sHp[0][t] + sHp[1][t] + sHp[2][t] + sHp[3][t];

  // --- coalesced T2 copy-out (overwrites msg0/em) ---
  uint4* dst = (uint4*)(em + (size_t)row * N * D);
  #pragma unroll
  for (int u = 0; u < 8; ++u) {
    const int idx4 = u * 256 + t;
    const int j = idx4 >> 4, g = idx4 & 15;
    dst[idx4] = sE4[j * 16 + (g ^ (j & 15))];
  }
}

// ---------------------------------------------------------------------------
// K6: final layer streaming: msg2 = relu(xi2 + xj2 + T2)*A; rowsum over j.
// Thread t: channels c8=(t&15)*8, j residue jr=t>>4 (8 j's per thread).
// ---------------------------------------------------------------------------
__global__ __launch_bounds__(256) void k_fin(
    const int* __restrict__ ei, const _Float16* __restrict__ t2,
    const float* __restrict__ xi, const float* __restrict__ xj,
    float* __restrict__ rowsum) {
  const int row = blockIdx.x;
  const int b = row >> 7;
  const int t = threadIdx.x;
  const int c8 = (t & 15) * 8, jr = t >> 4;

  __shared__ float sMask[N];
  __shared__ float hp[16][16][8];
  if (t < N) sMask[t] = (float)ei[(size_t)row * N + t];
  float xiv[8];
  *(floatx4*)&xiv[0] = *(const floatx4*)&xi[row * D + c8];
  *(floatx4*)&xiv[4] = *(const floatx4*)&xi[row * D + c8 + 4];
  __syncthreads();

  const uint4* src = (const uint4*)(t2 + (size_t)row * N * D);
  const float* xjb = xj + (size_t)b * N * D;
  float acc8[8] = {};
  #pragma unroll
  for (int u = 0; u < 8; ++u) {
    const int j = u * 16 + jr;
    const uint4 raw = src[u * 256 + t];
    const half8 tv = *(const half8*)&raw;
    const float am = sMask[j];
    const floatx4 xj0 = *(const floatx4*)&xjb[j * D + c8];
    const floatx4 xj1 = *(const floatx4*)&xjb[j * D + c8 + 4];
    #pragma unroll
    for (int r = 0; r < 4; ++r) {
      acc8[r]     += fmaxf(xiv[r] + xj0[r] + (float)tv[r], 0.f) * am;
      acc8[4 + r] += fmaxf(xiv[4 + r] + xj1[r] + (float)tv[4 + r], 0.f) * am;
    }
  }
  #pragma unroll
  for (int k = 0; k < 8; ++k) hp[jr][t & 15][k] = acc8[k];
  __syncthreads();
  if (t < D) {
    float s = 0.f;
    #pragma unroll
    for (int g = 0; g < 16; ++g) s += hp[g][t >> 3][t & 7];
    rowsum[row * D + t] = s;
  }
}

// ---------------------------------------------------------------------------
// K7: head MLP. 16 blocks.
// ---------------------------------------------------------------------------
__global__ __launch_bounds__(128) void k_head(
    const float* __restrict__ rowsum,
    const float* __restrict__ w1, const float* __restrict__ b1,
    const float* __restrict__ w2, const float* __restrict__ b2,
    const float* __restrict__ w3, const float* __restrict__ b3,
    float* __restrict__ out) {
  const int b = blockIdx.x;
  const int c = threadIdx.x;
  __shared__ float hr[D], h1r[D], h2r[D];
  const float* rs = rowsum + (size_t)b * N * D;
  float s = 0.f;
  for (int i = 0; i < N; ++i) s += rs[i * D + c];
  hr[c] = s * (1.f / (N * N));
  __syncthreads();
  float a = b1[c];
  #pragma unroll 8
  for (int k = 0; k < D; ++k) a = fmaf(hr[k], w1[k * D + c], a);
  h1r[c] = fmaxf(a, 0.f);
  __syncthreads();
  a = b2[c];
  #pragma unroll 8
  for (int k = 0; k < D; ++k) a = fmaf(h1r[k], w2[k * D + c], a);
  h2r[c] = fmaxf(a, 0.f);
  __syncthreads();
  hr[c] = h2r[c] * w3[c];
  __syncthreads();
  if (c == 0) {
    float s2 = b3[0];
    for (int k = 0; k < D; ++k) s2 += hr[k];
    out[b] = s2;
  }
}

// ---------------------------------------------------------------------------
extern "C" void kernel_launch(void* const* d_in, const int* in_sizes, int n_in,
                              void* d_out, int out_size, void* d_ws, size_t ws_size,
                              hipStream_t stream) {
  const int*   ei  = (const int*)d_in[0];
  const float* x0  = (const float*)d_in[1];
  const float* ea  = (const float*)d_in[2];
  const float* wm0 = (const float*)d_in[3];
  const float* bm0 = (const float*)d_in[4];
  const float* wn0 = (const float*)d_in[5];
  const float* bn0 = (const float*)d_in[6];
  const float* wm1 = (const float*)d_in[7];
  const float* bm1 = (const float*)d_in[8];
  const float* wn1 = (const float*)d_in[9];
  const float* bn1 = (const float*)d_in[10];
  const float* wm2 = (const float*)d_in[11];
  const float* bm2 = (const float*)d_in[12];
  const float* wh1 = (const float*)d_in[15];
  const float* bh1 = (const float*)d_in[16];
  const float* wh2 = (const float*)d_in[17];
  const float* bh2 = (const float*)d_in[18];
  const float* wh3 = (const float*)d_in[19];
  const float* bh3 = (const float*)d_in[20];
  float* out = (float*)d_out;

  _Float16* msg0h = (_Float16*)d_ws;                 // [B,N,N,D] fp16: msg0 -> T2
  _Float16* weT1  = msg0h + (size_t)B * N * N * D;
  _Float16* weT2  = weT1 + D * D;
  float* f = (float*)(weT2 + D * D);
  size_t off = 0;
  const size_t R = (size_t)B * N * D;
  float* xi0  = f + off; off += R;
  float* xj0  = f + off; off += R;
  float* agg0 = f + off; off += R;
  float* x1   = f + off; off += R;
  float* xi1  = f + off; off += R;
  float* xj1  = f + off; off += R;
  float* agg1 = f + off; off += R;
  float* xi2  = f + off; off += R;
  float* xj2  = f + off; off += R;
  float* rsum = f + off; off += R;

  const int rows = B * N;   // 2048
  k_wprep<<<256, 128, 0, stream>>>(wm1, wm2, weT1, weT2);
  k_pre0 <<<rows, 128, 0, stream>>>(x0, wm0, bm0, xi0, xj0);
  k_edge0<<<rows, 256, 0, stream>>>(ei, ea, wm0, xi0, xj0, msg0h, agg0);
  k_node0<<<rows, 128, 0, stream>>>(x0, agg0, wn0, bn0, wm1, bm1, x1, xi1, xj1);
  k_mid  <<<rows, 256, 0, stream>>>(ei, weT1, weT2, xi1, xj1, msg0h, agg1);
  k_node1<<<rows, 128, 0, stream>>>(x1, agg1, wn1, bn1, wm2, bm2, xi2, xj2);
  k_fin  <<<rows, 256, 0, stream>>>(ei, msg0h, xi2, xj2, rsum);
  k_head <<<B,    128, 0, stream>>>(rsum, wh1, bh1, wh2, bh2, wh3, bh3, out);
}